// Round 1
// baseline (352.854 us; speedup 1.0000x reference)
//
#include <hip/hip_runtime.h>

typedef unsigned short u16;
typedef unsigned int u32;
typedef __attribute__((ext_vector_type(4))) float f32x4;
typedef __attribute__((ext_vector_type(8))) short bf16x8;
typedef __attribute__((address_space(1))) const u32* gp1_t;
typedef __attribute__((address_space(3))) u32* lp3_t;

#define H 768
#define V 32000
#define MROWS 2048   // B*C*32 = 4*16*32

__device__ __forceinline__ u16 f2bf(float f) {
  u32 x = __float_as_uint(f);
  x += 0x7fffu + ((x >> 16) & 1u);   // round-to-nearest-even
  return (u16)(x >> 16);
}

// ---- kernel 0: compact list of active rows ----
__global__ void prep_kernel(const int* __restrict__ split, const int* __restrict__ nch,
                            int* __restrict__ row_list, int* __restrict__ count) {
  __shared__ int cnt;
  if (threadIdx.x == 0) cnt = 0;
  __syncthreads();
  for (int row = threadIdx.x; row < MROWS; row += blockDim.x) {
    int b = row >> 9;          // 512 rows per batch (16 chunks * 32 tok)
    int c = (row >> 5) & 15;
    int t = row & 31;
    if (c < nch[b] && t < split[b * 16 + c]) {
      int slot = atomicAdd(&cnt, 1);
      row_list[slot] = row;
    }
  }
  __syncthreads();
  if (threadIdx.x == 0) *count = cnt;
}

// ---- kernel 1: word_embeddings f32 -> bf16 ----
__global__ void conv_kernel(const float* __restrict__ in, u16* __restrict__ out, int n4) {
  int i = blockIdx.x * blockDim.x + threadIdx.x;
  int stride = gridDim.x * blockDim.x;
  for (; i < n4; i += stride) {
    float4 v = reinterpret_cast<const float4*>(in)[i];
    ushort4 o;
    o.x = f2bf(v.x); o.y = f2bf(v.y); o.z = f2bf(v.z); o.w = f2bf(v.w);
    reinterpret_cast<ushort4*>(out)[i] = o;
  }
}

// ---- kernel 2: u[row] = word_embeddings[tok[row]] @ W_dec (f32 math, bf16 out) ----
// 8 compacted rows per block, 256 threads; thread k handles output cols k, k+256, k+512.
__global__ void udec_kernel(const int* __restrict__ tok_ids, const float* __restrict__ wemb,
                            const float* __restrict__ wdec, const int* __restrict__ row_list,
                            const int* __restrict__ count, u16* __restrict__ u) {
  __shared__ float e[8][H];
  __shared__ int rows[8];
  int cnt = *count;
  int base = blockIdx.x * 8;
  if (base >= cnt) return;
  int nr = min(8, cnt - base);
  if (threadIdx.x < 8)
    rows[threadIdx.x] = (threadIdx.x < nr) ? row_list[base + threadIdx.x] : -1;
  __syncthreads();
  for (int r = 0; r < 8; ++r) {
    if (r < nr) {
      int row = rows[r];
      int tok = tok_ids[(row >> 5) * 33 + (row & 31)];   // (b*16+c)*33 + t
      const float* src = wemb + (size_t)tok * H;
      for (int h = threadIdx.x; h < H; h += blockDim.x) e[r][h] = src[h];
    } else {
      for (int h = threadIdx.x; h < H; h += blockDim.x) e[r][h] = 0.f;
    }
  }
  __syncthreads();
  const int k = threadIdx.x;
  float acc[3][8];
  #pragma unroll
  for (int kc = 0; kc < 3; ++kc)
    #pragma unroll
    for (int r = 0; r < 8; ++r) acc[kc][r] = 0.f;
  for (int h = 0; h < H; ++h) {
    float w0 = wdec[(size_t)h * H + k];
    float w1 = wdec[(size_t)h * H + k + 256];
    float w2 = wdec[(size_t)h * H + k + 512];
    #pragma unroll
    for (int r = 0; r < 8; ++r) {
      float ev = e[r][h];
      acc[0][r] += ev * w0;
      acc[1][r] += ev * w1;
      acc[2][r] += ev * w2;
    }
  }
  for (int r = 0; r < nr; ++r) {
    size_t o = (size_t)rows[r] * H + k;
    u[o]       = f2bf(acc[0][r]);
    u[o + 256] = f2bf(acc[1][r]);
    u[o + 512] = f2bf(acc[2][r]);
  }
}

// ---- kernel 3: C[M,V] = U[M,H] x Wemb[V,H]^T  (bf16 MFMA, f32 accum) ----
// 128x128 tile, BK=64, 4 waves (2x2), each wave 64x64 = 4x4 frags of 16x16x32.
#define BM 128
#define BN 128
#define BK 64

__global__ __launch_bounds__(256) void gemm_kernel(const u16* __restrict__ A,
                                                   const u16* __restrict__ Bm,
                                                   float* __restrict__ C) {
  __shared__ u16 As[BM * BK];
  __shared__ u16 Bs[BN * BK];
  const int tid = threadIdx.x;
  const int wave = tid >> 6;
  const int lane = tid & 63;
  const int wm = (wave >> 1) * 64;
  const int wn = (wave & 1) * 64;
  const int fr = lane & 15;
  const int fq = lane >> 4;
  const size_t m0 = (size_t)blockIdx.y * BM;
  const size_t n0 = (size_t)blockIdx.x * BN;
  const u16* Abase = A + m0 * H;
  const u16* Bbase = Bm + n0 * H;

  f32x4 acc[4][4];
  const f32x4 z = {0.f, 0.f, 0.f, 0.f};
  #pragma unroll
  for (int i = 0; i < 4; ++i)
    #pragma unroll
    for (int j = 0; j < 4; ++j) acc[i][j] = z;

  for (int k0 = 0; k0 < H; k0 += BK) {
    // stage A,B tiles (row-major [128][64] bf16) via direct global->LDS, 16B/lane
    #pragma unroll
    for (int i = 0; i < 4; ++i) {
      int e = (i * 256 + tid) * 8;   // element index in tile, lane-contiguous
      int row = e >> 6;
      int col = e & 63;
      __builtin_amdgcn_global_load_lds((gp1_t)(Abase + (size_t)row * H + k0 + col),
                                       (lp3_t)(&As[e]), 16, 0, 0);
      __builtin_amdgcn_global_load_lds((gp1_t)(Bbase + (size_t)row * H + k0 + col),
                                       (lp3_t)(&Bs[e]), 16, 0, 0);
    }
    __syncthreads();
    #pragma unroll
    for (int kk = 0; kk < BK; kk += 32) {
      bf16x8 af[4], bfr[4];
      #pragma unroll
      for (int mi = 0; mi < 4; ++mi)
        af[mi] = *reinterpret_cast<const bf16x8*>(&As[(wm + mi * 16 + fr) * BK + kk + fq * 8]);
      #pragma unroll
      for (int ni = 0; ni < 4; ++ni)
        bfr[ni] = *reinterpret_cast<const bf16x8*>(&Bs[(wn + ni * 16 + fr) * BK + kk + fq * 8]);
      #pragma unroll
      for (int mi = 0; mi < 4; ++mi)
        #pragma unroll
        for (int ni = 0; ni < 4; ++ni)
          acc[mi][ni] = __builtin_amdgcn_mfma_f32_16x16x32_bf16(af[mi], bfr[ni], acc[mi][ni], 0, 0, 0);
    }
    __syncthreads();
  }

  // C/D layout: col = lane&15, row = (lane>>4)*4 + reg
  float* Cbase = C + (m0 + wm) * (size_t)V + n0 + wn;
  #pragma unroll
  for (int mi = 0; mi < 4; ++mi)
    #pragma unroll
    for (int ni = 0; ni < 4; ++ni)
      #pragma unroll
      for (int v = 0; v < 4; ++v)
        Cbase[(size_t)(mi * 16 + fq * 4 + v) * V + ni * 16 + fr] = acc[mi][ni][v];
}

extern "C" void kernel_launch(void* const* d_in, const int* in_sizes, int n_in,
                              void* d_out, int out_size, void* d_ws, size_t ws_size,
                              hipStream_t stream) {
  const int* tok    = (const int*)d_in[0];    // (4,16,33) int32
  const int* split  = (const int*)d_in[1];    // (4,16) int32
  const int* nch    = (const int*)d_in[2];    // (4,) int32
  // d_in[3] chunk_units, d_in[5] chunk_sos_embedding: provably dead w.r.t. output
  const float* wemb = (const float*)d_in[4];  // (32000,768) f32
  const float* wdec = (const float*)d_in[6];  // (768,768) f32
  float* out = (float*)d_out;                 // (4,16,32,32000) f32

  char* ws = (char*)d_ws;
  u16* wemb_bf  = (u16*)ws;                                   // 49,152,000 B
  u16* u        = (u16*)(ws + 49152000);                      //  3,145,728 B
  int* row_list = (int*)(ws + 49152000 + 3145728);            //      8,192 B
  int* count    = row_list + MROWS;

  hipMemsetAsync(u, 0, (size_t)MROWS * H * sizeof(u16), stream);
  prep_kernel<<<1, 256, 0, stream>>>(split, nch, row_list, count);
  conv_kernel<<<2048, 256, 0, stream>>>(wemb, wemb_bf, V * H / 4);
  udec_kernel<<<256, 256, 0, stream>>>(tok, wemb, wdec, row_list, count, u);
  gemm_kernel<<<dim3(V / BN, MROWS / BM), 256, 0, stream>>>(u, wemb_bf, out);
}

// Round 2
// 306.400 us; speedup vs baseline: 1.1516x; 1.1516x over previous
//
#include <hip/hip_runtime.h>

typedef unsigned short u16;
typedef unsigned int u32;
typedef __attribute__((ext_vector_type(4))) float f32x4;
typedef __attribute__((ext_vector_type(8))) short bf16x8;
typedef __attribute__((address_space(1))) const u32* gp1_t;
typedef __attribute__((address_space(3))) u32* lp3_t;

#define H 768
#define V 32000
#define MROWS 2048   // B*C*32 = 4*16*32

__device__ __forceinline__ u16 f2bf(float f) {
  u32 x = __float_as_uint(f);
  x += 0x7fffu + ((x >> 16) & 1u);   // round-to-nearest-even
  return (u16)(x >> 16);
}

// ---- kernel 0: compact list of active rows ----
__global__ void prep_kernel(const int* __restrict__ split, const int* __restrict__ nch,
                            int* __restrict__ row_list, int* __restrict__ count) {
  __shared__ int cnt;
  if (threadIdx.x == 0) cnt = 0;
  __syncthreads();
  for (int row = threadIdx.x; row < MROWS; row += blockDim.x) {
    int b = row >> 9;          // 512 rows per batch (16 chunks * 32 tok)
    int c = (row >> 5) & 15;
    int t = row & 31;
    if (c < nch[b] && t < split[b * 16 + c]) {
      int slot = atomicAdd(&cnt, 1);
      row_list[slot] = row;
    }
  }
  __syncthreads();
  if (threadIdx.x == 0) *count = cnt;
}

// ---- kernel 1: word_embeddings f32 -> bf16 ----
__global__ void conv_kernel(const float* __restrict__ in, u16* __restrict__ out, int n4) {
  int i = blockIdx.x * blockDim.x + threadIdx.x;
  int stride = gridDim.x * blockDim.x;
  for (; i < n4; i += stride) {
    float4 v = reinterpret_cast<const float4*>(in)[i];
    ushort4 o;
    o.x = f2bf(v.x); o.y = f2bf(v.y); o.z = f2bf(v.z); o.w = f2bf(v.w);
    reinterpret_cast<ushort4*>(out)[i] = o;
  }
}

// ---- kernel 2: zero-fill INACTIVE output rows (active rows written by gemm) ----
__global__ void zfill_kernel(const int* __restrict__ split, const int* __restrict__ nch,
                             float* __restrict__ out) {
  int row = blockIdx.x;
  int b = row >> 9;
  int c = (row >> 5) & 15;
  int t = row & 31;
  if (c < nch[b] && t < split[b * 16 + c]) return;   // active -> gemm writes it
  float4 z = {0.f, 0.f, 0.f, 0.f};
  float4* p = reinterpret_cast<float4*>(out + (size_t)row * V);
  for (int i = threadIdx.x; i < V / 4; i += blockDim.x) p[i] = z;
}

// ---- kernel 3: u[slot] = word_embeddings[tok[row_list[slot]]] @ W_dec ----
// f32 math, bf16 out at COMPACTED positions. 8 rows/block, 768 threads (12 waves),
// one output column per thread, unrolled so 8 wdec loads stay in flight.
__global__ __launch_bounds__(768) void udec_kernel(const int* __restrict__ tok_ids,
                                                   const float* __restrict__ wemb,
                                                   const float* __restrict__ wdec,
                                                   const int* __restrict__ row_list,
                                                   const int* __restrict__ count,
                                                   u16* __restrict__ u) {
  __shared__ float e[8][H];
  __shared__ int rows[8];
  int cnt = *count;
  int base = blockIdx.x * 8;
  if (base >= cnt) return;
  int nr = min(8, cnt - base);
  if (threadIdx.x < 8)
    rows[threadIdx.x] = (threadIdx.x < nr) ? row_list[base + threadIdx.x] : -1;
  __syncthreads();
  #pragma unroll
  for (int r = 0; r < 8; ++r) {
    if (r < nr) {
      int row = rows[r];
      int tok = tok_ids[(row >> 5) * 33 + (row & 31)];   // (b*16+c)*33 + t
      e[r][threadIdx.x] = wemb[(size_t)tok * H + threadIdx.x];
    } else {
      e[r][threadIdx.x] = 0.f;
    }
  }
  __syncthreads();
  const int k = threadIdx.x;
  float acc[8];
  #pragma unroll
  for (int r = 0; r < 8; ++r) acc[r] = 0.f;
  #pragma unroll 8
  for (int h = 0; h < H; ++h) {
    float w = wdec[(size_t)h * H + k];
    #pragma unroll
    for (int r = 0; r < 8; ++r) acc[r] += e[r][h] * w;
  }
  for (int r = 0; r < nr; ++r)
    u[(size_t)(base + r) * H + k] = f2bf(acc[r]);
}

// ---- kernel 4: out[row_list[m],:] = U[m,:] x Wemb[V,H]^T  (bf16 MFMA, f32 accum) ----
// 128x128 tile, BK=64, 4 waves (2x2), each wave 64x64 = 4x4 frags of 16x16x32.
// M is compacted; scatter rows to output via row_list.
#define BM 128
#define BN 128
#define BK 64

__global__ __launch_bounds__(256) void gemm_kernel(const u16* __restrict__ A,
                                                   const u16* __restrict__ Bm,
                                                   const int* __restrict__ row_list,
                                                   const int* __restrict__ count,
                                                   float* __restrict__ C) {
  const int cnt = *count;
  const int m0i = blockIdx.y * BM;
  if (m0i >= cnt) return;
  __shared__ u16 As[BM * BK];
  __shared__ u16 Bs[BN * BK];
  __shared__ int rowmap[BM];
  const int tid = threadIdx.x;
  const int wave = tid >> 6;
  const int lane = tid & 63;
  const int wm = (wave >> 1) * 64;
  const int wn = (wave & 1) * 64;
  const int fr = lane & 15;
  const int fq = lane >> 4;
  const size_t m0 = (size_t)m0i;
  const size_t n0 = (size_t)blockIdx.x * BN;
  const u16* Abase = A + m0 * H;
  const u16* Bbase = Bm + n0 * H;
  if (tid < BM)
    rowmap[tid] = (m0i + tid < cnt) ? row_list[m0i + tid] : -1;

  f32x4 acc[4][4];
  const f32x4 z = {0.f, 0.f, 0.f, 0.f};
  #pragma unroll
  for (int i = 0; i < 4; ++i)
    #pragma unroll
    for (int j = 0; j < 4; ++j) acc[i][j] = z;

  for (int k0 = 0; k0 < H; k0 += BK) {
    #pragma unroll
    for (int i = 0; i < 4; ++i) {
      int e = (i * 256 + tid) * 8;   // element index in tile, lane-contiguous
      int row = e >> 6;
      int col = e & 63;
      __builtin_amdgcn_global_load_lds((gp1_t)(Abase + (size_t)row * H + k0 + col),
                                       (lp3_t)(&As[e]), 16, 0, 0);
      __builtin_amdgcn_global_load_lds((gp1_t)(Bbase + (size_t)row * H + k0 + col),
                                       (lp3_t)(&Bs[e]), 16, 0, 0);
    }
    __syncthreads();
    #pragma unroll
    for (int kk = 0; kk < BK; kk += 32) {
      bf16x8 af[4], bfr[4];
      #pragma unroll
      for (int mi = 0; mi < 4; ++mi)
        af[mi] = *reinterpret_cast<const bf16x8*>(&As[(wm + mi * 16 + fr) * BK + kk + fq * 8]);
      #pragma unroll
      for (int ni = 0; ni < 4; ++ni)
        bfr[ni] = *reinterpret_cast<const bf16x8*>(&Bs[(wn + ni * 16 + fr) * BK + kk + fq * 8]);
      #pragma unroll
      for (int mi = 0; mi < 4; ++mi)
        #pragma unroll
        for (int ni = 0; ni < 4; ++ni)
          acc[mi][ni] = __builtin_amdgcn_mfma_f32_16x16x32_bf16(af[mi], bfr[ni], acc[mi][ni], 0, 0, 0);
    }
    __syncthreads();
  }

  // C/D layout: col = lane&15, row = (lane>>4)*4 + reg; scatter rows via rowmap
  #pragma unroll
  for (int mi = 0; mi < 4; ++mi) {
    #pragma unroll
    for (int v = 0; v < 4; ++v) {
      int m = wm + mi * 16 + fq * 4 + v;
      int orow = rowmap[m];
      if (orow < 0) continue;
      float* cb = C + (size_t)orow * V + n0 + wn;
      #pragma unroll
      for (int ni = 0; ni < 4; ++ni)
        cb[ni * 16 + fr] = acc[mi][ni][v];
    }
  }
}

extern "C" void kernel_launch(void* const* d_in, const int* in_sizes, int n_in,
                              void* d_out, int out_size, void* d_ws, size_t ws_size,
                              hipStream_t stream) {
  const int* tok    = (const int*)d_in[0];    // (4,16,33) int32
  const int* split  = (const int*)d_in[1];    // (4,16) int32
  const int* nch    = (const int*)d_in[2];    // (4,) int32
  // d_in[3] chunk_units, d_in[5] chunk_sos_embedding: provably dead w.r.t. output
  const float* wemb = (const float*)d_in[4];  // (32000,768) f32
  const float* wdec = (const float*)d_in[6];  // (768,768) f32
  float* out = (float*)d_out;                 // (4,16,32,32000) f32

  char* ws = (char*)d_ws;
  u16* wemb_bf  = (u16*)ws;                                   // 49,152,000 B
  u16* u        = (u16*)(ws + 49152000);                      //  3,145,728 B
  int* row_list = (int*)(ws + 49152000 + 3145728);            //      8,192 B
  int* count    = row_list + MROWS;

  hipMemsetAsync(u, 0, (size_t)MROWS * H * sizeof(u16), stream);
  prep_kernel<<<1, 256, 0, stream>>>(split, nch, row_list, count);
  udec_kernel<<<MROWS / 8, 768, 0, stream>>>(tok, wemb, wdec, row_list, count, u);
  conv_kernel<<<2048, 256, 0, stream>>>(wemb, wemb_bf, V * H / 4);
  zfill_kernel<<<MROWS, 256, 0, stream>>>(split, nch, out);
  gemm_kernel<<<dim3(V / BN, MROWS / BM), 256, 0, stream>>>(u, wemb_bf, row_list, count, out);
}

// Round 3
// 158.789 us; speedup vs baseline: 2.2221x; 1.9296x over previous
//
#include <hip/hip_runtime.h>

typedef unsigned short u16;
typedef unsigned int u32;
typedef __attribute__((ext_vector_type(4))) float f32x4;
typedef __attribute__((ext_vector_type(8))) short bf16x8;
typedef __attribute__((address_space(1))) const u32* gp1_t;
typedef __attribute__((address_space(3))) u32* lp3_t;

#define H 768
#define V 32000
#define MROWS 2048   // B*C*32 = 4*16*32

__device__ __forceinline__ u16 f2bf(float f) {
  u32 x = __float_as_uint(f);
  x += 0x7fffu + ((x >> 16) & 1u);   // round-to-nearest-even
  return (u16)(x >> 16);
}

// ---- kernel 0: compact list of active rows ----
__global__ void prep_kernel(const int* __restrict__ split, const int* __restrict__ nch,
                            int* __restrict__ row_list, int* __restrict__ count) {
  __shared__ int cnt;
  if (threadIdx.x == 0) cnt = 0;
  __syncthreads();
  for (int row = threadIdx.x; row < MROWS; row += blockDim.x) {
    int b = row >> 9;          // 512 rows per batch (16 chunks * 32 tok)
    int c = (row >> 5) & 15;
    int t = row & 31;
    if (c < nch[b] && t < split[b * 16 + c]) {
      int slot = atomicAdd(&cnt, 1);
      row_list[slot] = row;
    }
  }
  __syncthreads();
  if (threadIdx.x == 0) *count = cnt;
}

// ---- kernel 1: word_embeddings f32 -> bf16 ----
__global__ void conv_kernel(const float* __restrict__ in, u16* __restrict__ out, int n4) {
  int i = blockIdx.x * blockDim.x + threadIdx.x;
  int stride = gridDim.x * blockDim.x;
  for (; i < n4; i += stride) {
    float4 v = reinterpret_cast<const float4*>(in)[i];
    ushort4 o;
    o.x = f2bf(v.x); o.y = f2bf(v.y); o.z = f2bf(v.z); o.w = f2bf(v.w);
    reinterpret_cast<ushort4*>(out)[i] = o;
  }
}

// ---- kernel 2: zero-fill INACTIVE output rows (active rows written by gemm) ----
__global__ void zfill_kernel(const int* __restrict__ split, const int* __restrict__ nch,
                             float* __restrict__ out) {
  int row = blockIdx.x;
  int b = row >> 9;
  int c = (row >> 5) & 15;
  int t = row & 31;
  if (c < nch[b] && t < split[b * 16 + c]) return;   // active -> gemm writes it
  float4 z = {0.f, 0.f, 0.f, 0.f};
  float4* p = reinterpret_cast<float4*>(out + (size_t)row * V);
  for (int i = threadIdx.x; i < V / 4; i += blockDim.x) p[i] = z;
}

// ---- kernel 3a: gather + convert E rows (compacted, zero-padded to MROWS) ----
// e_bf[slot][h] = bf16(wemb[tok[row_list[slot]]][h]), zeros for slot >= cnt.
__global__ void egather_kernel(const int* __restrict__ tok_ids, const float* __restrict__ wemb,
                               const int* __restrict__ row_list, const int* __restrict__ count,
                               u16* __restrict__ e_bf) {
  int s = blockIdx.x;
  int cnt = *count;
  int c4 = threadIdx.x * 4;          // 192 threads x 4 elems = 768
  ushort4 o = {0, 0, 0, 0};
  if (s < cnt) {
    int row = row_list[s];
    int tok = tok_ids[(row >> 5) * 33 + (row & 31)];
    float4 v = *reinterpret_cast<const float4*>(&wemb[(size_t)tok * H + c4]);
    o.x = f2bf(v.x); o.y = f2bf(v.y); o.z = f2bf(v.z); o.w = f2bf(v.w);
  }
  *reinterpret_cast<ushort4*>(&e_bf[(size_t)s * H + c4]) = o;
}

// ---- kernel 3b: W_dec transpose + convert: wdecT[j][h] = bf16(wdec[h][j]) ----
__global__ void wdecT_kernel(const float* __restrict__ wdec, u16* __restrict__ wdecT) {
  __shared__ float tile[64][65];
  int hb = blockIdx.x * 64, jb = blockIdx.y * 64;
  #pragma unroll
  for (int rr = 0; rr < 64; rr += 16) {
    int r = rr + (threadIdx.x >> 4);
    int c = (threadIdx.x & 15) * 4;
    float4 v = *reinterpret_cast<const float4*>(&wdec[(size_t)(hb + r) * H + jb + c]);
    tile[r][c] = v.x; tile[r][c + 1] = v.y; tile[r][c + 2] = v.z; tile[r][c + 3] = v.w;
  }
  __syncthreads();
  #pragma unroll
  for (int rr = 0; rr < 64; rr += 16) {
    int r = rr + (threadIdx.x >> 4);      // j
    int c = (threadIdx.x & 15) * 4;       // h group
    ushort4 o;
    o.x = f2bf(tile[c][r]); o.y = f2bf(tile[c + 1][r]);
    o.z = f2bf(tile[c + 2][r]); o.w = f2bf(tile[c + 3][r]);
    *reinterpret_cast<ushort4*>(&wdecT[(size_t)(jb + r) * H + hb + c]) = o;
  }
}

// ---- kernel 3c: u[slot,:] = E[slot,:] x WdecT[768,768]^T (bf16 MFMA, bf16 out) ----
// Same verified 128x128xBK64 structure as main gemm; output row-major [MROWS][H] bf16.
#define BM 128
#define BN 128
#define BK 64

__global__ __launch_bounds__(256) void udec_gemm_kernel(const u16* __restrict__ A,
                                                        const u16* __restrict__ Bm,
                                                        const int* __restrict__ count,
                                                        u16* __restrict__ U) {
  const int cnt = *count;
  const int m0i = blockIdx.y * BM;
  if (m0i >= cnt) return;
  __shared__ u16 As[BM * BK];
  __shared__ u16 Bs[BN * BK];
  const int tid = threadIdx.x;
  const int wave = tid >> 6;
  const int lane = tid & 63;
  const int wm = (wave >> 1) * 64;
  const int wn = (wave & 1) * 64;
  const int fr = lane & 15;
  const int fq = lane >> 4;
  const size_t m0 = (size_t)m0i;
  const size_t n0 = (size_t)blockIdx.x * BN;
  const u16* Abase = A + m0 * H;
  const u16* Bbase = Bm + n0 * H;

  f32x4 acc[4][4];
  const f32x4 z = {0.f, 0.f, 0.f, 0.f};
  #pragma unroll
  for (int i = 0; i < 4; ++i)
    #pragma unroll
    for (int j = 0; j < 4; ++j) acc[i][j] = z;

  for (int k0 = 0; k0 < H; k0 += BK) {
    #pragma unroll
    for (int i = 0; i < 4; ++i) {
      int e = (i * 256 + tid) * 8;
      int row = e >> 6;
      int col = e & 63;
      __builtin_amdgcn_global_load_lds((gp1_t)(Abase + (size_t)row * H + k0 + col),
                                       (lp3_t)(&As[e]), 16, 0, 0);
      __builtin_amdgcn_global_load_lds((gp1_t)(Bbase + (size_t)row * H + k0 + col),
                                       (lp3_t)(&Bs[e]), 16, 0, 0);
    }
    __syncthreads();
    #pragma unroll
    for (int kk = 0; kk < BK; kk += 32) {
      bf16x8 af[4], bfr[4];
      #pragma unroll
      for (int mi = 0; mi < 4; ++mi)
        af[mi] = *reinterpret_cast<const bf16x8*>(&As[(wm + mi * 16 + fr) * BK + kk + fq * 8]);
      #pragma unroll
      for (int ni = 0; ni < 4; ++ni)
        bfr[ni] = *reinterpret_cast<const bf16x8*>(&Bs[(wn + ni * 16 + fr) * BK + kk + fq * 8]);
      #pragma unroll
      for (int mi = 0; mi < 4; ++mi)
        #pragma unroll
        for (int ni = 0; ni < 4; ++ni)
          acc[mi][ni] = __builtin_amdgcn_mfma_f32_16x16x32_bf16(af[mi], bfr[ni], acc[mi][ni], 0, 0, 0);
    }
    __syncthreads();
  }

  // C/D layout: col = lane&15, row = (lane>>4)*4 + reg
  u16* Ubase = U + (m0 + wm) * (size_t)H + n0 + wn;
  #pragma unroll
  for (int mi = 0; mi < 4; ++mi)
    #pragma unroll
    for (int ni = 0; ni < 4; ++ni)
      #pragma unroll
      for (int v = 0; v < 4; ++v)
        Ubase[(size_t)(mi * 16 + fq * 4 + v) * H + ni * 16 + fr] = f2bf(acc[mi][ni][v]);
}

// ---- kernel 4: out[row_list[m],:] = U[m,:] x Wemb[V,H]^T  (bf16 MFMA, f32 accum) ----
__global__ __launch_bounds__(256) void gemm_kernel(const u16* __restrict__ A,
                                                   const u16* __restrict__ Bm,
                                                   const int* __restrict__ row_list,
                                                   const int* __restrict__ count,
                                                   float* __restrict__ C) {
  const int cnt = *count;
  const int m0i = blockIdx.y * BM;
  if (m0i >= cnt) return;
  __shared__ u16 As[BM * BK];
  __shared__ u16 Bs[BN * BK];
  __shared__ int rowmap[BM];
  const int tid = threadIdx.x;
  const int wave = tid >> 6;
  const int lane = tid & 63;
  const int wm = (wave >> 1) * 64;
  const int wn = (wave & 1) * 64;
  const int fr = lane & 15;
  const int fq = lane >> 4;
  const size_t m0 = (size_t)m0i;
  const size_t n0 = (size_t)blockIdx.x * BN;
  const u16* Abase = A + m0 * H;
  const u16* Bbase = Bm + n0 * H;
  if (tid < BM)
    rowmap[tid] = (m0i + tid < cnt) ? row_list[m0i + tid] : -1;

  f32x4 acc[4][4];
  const f32x4 z = {0.f, 0.f, 0.f, 0.f};
  #pragma unroll
  for (int i = 0; i < 4; ++i)
    #pragma unroll
    for (int j = 0; j < 4; ++j) acc[i][j] = z;

  for (int k0 = 0; k0 < H; k0 += BK) {
    #pragma unroll
    for (int i = 0; i < 4; ++i) {
      int e = (i * 256 + tid) * 8;
      int row = e >> 6;
      int col = e & 63;
      __builtin_amdgcn_global_load_lds((gp1_t)(Abase + (size_t)row * H + k0 + col),
                                       (lp3_t)(&As[e]), 16, 0, 0);
      __builtin_amdgcn_global_load_lds((gp1_t)(Bbase + (size_t)row * H + k0 + col),
                                       (lp3_t)(&Bs[e]), 16, 0, 0);
    }
    __syncthreads();
    #pragma unroll
    for (int kk = 0; kk < BK; kk += 32) {
      bf16x8 af[4], bfr[4];
      #pragma unroll
      for (int mi = 0; mi < 4; ++mi)
        af[mi] = *reinterpret_cast<const bf16x8*>(&As[(wm + mi * 16 + fr) * BK + kk + fq * 8]);
      #pragma unroll
      for (int ni = 0; ni < 4; ++ni)
        bfr[ni] = *reinterpret_cast<const bf16x8*>(&Bs[(wn + ni * 16 + fr) * BK + kk + fq * 8]);
      #pragma unroll
      for (int mi = 0; mi < 4; ++mi)
        #pragma unroll
        for (int ni = 0; ni < 4; ++ni)
          acc[mi][ni] = __builtin_amdgcn_mfma_f32_16x16x32_bf16(af[mi], bfr[ni], acc[mi][ni], 0, 0, 0);
    }
    __syncthreads();
  }

  // C/D layout: col = lane&15, row = (lane>>4)*4 + reg; scatter rows via rowmap
  #pragma unroll
  for (int mi = 0; mi < 4; ++mi) {
    #pragma unroll
    for (int v = 0; v < 4; ++v) {
      int m = wm + mi * 16 + fq * 4 + v;
      int orow = rowmap[m];
      if (orow < 0) continue;
      float* cb = C + (size_t)orow * V + n0 + wn;
      #pragma unroll
      for (int ni = 0; ni < 4; ++ni)
        cb[ni * 16 + fr] = acc[mi][ni][v];
    }
  }
}

extern "C" void kernel_launch(void* const* d_in, const int* in_sizes, int n_in,
                              void* d_out, int out_size, void* d_ws, size_t ws_size,
                              hipStream_t stream) {
  const int* tok    = (const int*)d_in[0];    // (4,16,33) int32
  const int* split  = (const int*)d_in[1];    // (4,16) int32
  const int* nch    = (const int*)d_in[2];    // (4,) int32
  // d_in[3] chunk_units, d_in[5] chunk_sos_embedding: provably dead w.r.t. output
  const float* wemb = (const float*)d_in[4];  // (32000,768) f32
  const float* wdec = (const float*)d_in[6];  // (768,768) f32
  float* out = (float*)d_out;                 // (4,16,32,32000) f32

  char* ws = (char*)d_ws;
  u16* wemb_bf  = (u16*)ws;                                   // 49,152,000 B
  u16* u        = (u16*)(ws + 49152000);                      //  3,145,728 B
  u16* e_bf     = (u16*)(ws + 49152000 + 3145728);            //  3,145,728 B
  u16* wdecT    = (u16*)(ws + 49152000 + 2 * 3145728);        //  1,179,648 B
  int* row_list = (int*)(ws + 49152000 + 2 * 3145728 + 1179648);
  int* count    = row_list + MROWS;

  hipMemsetAsync(u, 0, (size_t)MROWS * H * sizeof(u16), stream);
  prep_kernel<<<1, 256, 0, stream>>>(split, nch, row_list, count);
  egather_kernel<<<MROWS, 192, 0, stream>>>(tok, wemb, row_list, count, e_bf);
  wdecT_kernel<<<dim3(H / 64, H / 64), 256, 0, stream>>>(wdec, wdecT);
  udec_gemm_kernel<<<dim3(H / BN, MROWS / BM), 256, 0, stream>>>(e_bf, wdecT, count, u);
  conv_kernel<<<2048, 256, 0, stream>>>(wemb, wemb_bf, V * H / 4);
  zfill_kernel<<<MROWS, 256, 0, stream>>>(split, nch, out);
  gemm_kernel<<<dim3(V / BN, MROWS / BM), 256, 0, stream>>>(u, wemb_bf, row_list, count, out);
}

// Round 6
// 140.213 us; speedup vs baseline: 2.5165x; 1.1325x over previous
//
#include <hip/hip_runtime.h>

typedef unsigned short u16;
typedef unsigned int u32;
typedef __attribute__((ext_vector_type(4))) float f32x4;
typedef __attribute__((ext_vector_type(8))) short bf16x8;
typedef __attribute__((address_space(1))) const u32* gp1_t;
typedef __attribute__((address_space(3))) u32* lp3_t;

#define H 768
#define V 32000
#define MROWS 2048   // B*C*32 = 4*16*32

__device__ __forceinline__ u16 f2bf(float f) {
  u32 x = __float_as_uint(f);
  x += 0x7fffu + ((x >> 16) & 1u);   // round-to-nearest-even
  return (u16)(x >> 16);
}

// ---- kernel 0: compact list of active rows ----
__global__ void prep_kernel(const int* __restrict__ split, const int* __restrict__ nch,
                            int* __restrict__ row_list, int* __restrict__ count) {
  __shared__ int cnt;
  if (threadIdx.x == 0) cnt = 0;
  __syncthreads();
  for (int row = threadIdx.x; row < MROWS; row += blockDim.x) {
    int b = row >> 9;
    int c = (row >> 5) & 15;
    int t = row & 31;
    if (c < nch[b] && t < split[b * 16 + c]) {
      int slot = atomicAdd(&cnt, 1);
      row_list[slot] = row;
    }
  }
  __syncthreads();
  if (threadIdx.x == 0) *count = cnt;
}

// ---- kernel 1: merged {W_dec transpose->bf16} + {E-row gather->bf16} ----
__global__ void prep2_kernel(const float* __restrict__ wdec, u16* __restrict__ wdecT,
                             const int* __restrict__ tok_ids, const float* __restrict__ wemb,
                             const int* __restrict__ row_list, const int* __restrict__ count,
                             u16* __restrict__ e_bf) {
  if (blockIdx.x < 144) {
    __shared__ float tile[64][65];
    int b = blockIdx.x;
    int hb = (b / 12) * 64, jb = (b % 12) * 64;
    #pragma unroll
    for (int rr = 0; rr < 64; rr += 16) {
      int r = rr + (threadIdx.x >> 4);
      int c = (threadIdx.x & 15) * 4;
      float4 v = *reinterpret_cast<const float4*>(&wdec[(size_t)(hb + r) * H + jb + c]);
      tile[r][c] = v.x; tile[r][c + 1] = v.y; tile[r][c + 2] = v.z; tile[r][c + 3] = v.w;
    }
    __syncthreads();
    #pragma unroll
    for (int rr = 0; rr < 64; rr += 16) {
      int r = rr + (threadIdx.x >> 4);      // j
      int c = (threadIdx.x & 15) * 4;       // h group
      ushort4 o;
      o.x = f2bf(tile[c][r]); o.y = f2bf(tile[c + 1][r]);
      o.z = f2bf(tile[c + 2][r]); o.w = f2bf(tile[c + 3][r]);
      *reinterpret_cast<ushort4*>(&wdecT[(size_t)(jb + r) * H + hb + c]) = o;
    }
  } else {
    int s = blockIdx.x - 144;
    int cnt = *count;
    int c4 = threadIdx.x * 4;
    if (c4 >= H) return;
    ushort4 o = {0, 0, 0, 0};
    if (s < cnt) {
      int row = row_list[s];
      int tok = tok_ids[(row >> 5) * 33 + (row & 31)];
      float4 v = *reinterpret_cast<const float4*>(&wemb[(size_t)tok * H + c4]);
      o.x = f2bf(v.x); o.y = f2bf(v.y); o.z = f2bf(v.z); o.w = f2bf(v.w);
    }
    *reinterpret_cast<ushort4*>(&e_bf[(size_t)s * H + c4]) = o;
  }
}

// ---- kernel 2: u[slot,:] = E[slot,:] x WdecT^T (bf16 MFMA) — proven 128^2 structure ----
#define UBM 128
#define UBN 128
#define UBK 64

__global__ __launch_bounds__(256) void udec_gemm_kernel(const u16* __restrict__ A,
                                                        const u16* __restrict__ Bm,
                                                        const int* __restrict__ count,
                                                        u16* __restrict__ U) {
  const int cnt = *count;
  const int m0i = blockIdx.y * UBM;
  if (m0i >= cnt) return;
  __shared__ u16 As[UBM * UBK];
  __shared__ u16 Bs[UBN * UBK];
  const int tid = threadIdx.x;
  const int wave = tid >> 6;
  const int lane = tid & 63;
  const int wm = (wave >> 1) * 64;
  const int wn = (wave & 1) * 64;
  const int fr = lane & 15;
  const int fq = lane >> 4;
  const size_t m0 = (size_t)m0i;
  const size_t n0 = (size_t)blockIdx.x * UBN;
  const u16* Abase = A + m0 * H;
  const u16* Bbase = Bm + n0 * H;

  f32x4 acc[4][4];
  const f32x4 z = {0.f, 0.f, 0.f, 0.f};
  #pragma unroll
  for (int i = 0; i < 4; ++i)
    #pragma unroll
    for (int j = 0; j < 4; ++j) acc[i][j] = z;

  for (int k0 = 0; k0 < H; k0 += UBK) {
    #pragma unroll
    for (int i = 0; i < 4; ++i) {
      int e = (i * 256 + tid) * 8;
      int row = e >> 6;
      int col = e & 63;
      __builtin_amdgcn_global_load_lds((gp1_t)(Abase + (size_t)row * H + k0 + col),
                                       (lp3_t)(&As[e]), 16, 0, 0);
      __builtin_amdgcn_global_load_lds((gp1_t)(Bbase + (size_t)row * H + k0 + col),
                                       (lp3_t)(&Bs[e]), 16, 0, 0);
    }
    __syncthreads();
    #pragma unroll
    for (int kk = 0; kk < UBK; kk += 32) {
      bf16x8 af[4], bfr[4];
      #pragma unroll
      for (int mi = 0; mi < 4; ++mi)
        af[mi] = *reinterpret_cast<const bf16x8*>(&As[(wm + mi * 16 + fr) * UBK + kk + fq * 8]);
      #pragma unroll
      for (int ni = 0; ni < 4; ++ni)
        bfr[ni] = *reinterpret_cast<const bf16x8*>(&Bs[(wn + ni * 16 + fr) * UBK + kk + fq * 8]);
      #pragma unroll
      for (int mi = 0; mi < 4; ++mi)
        #pragma unroll
        for (int ni = 0; ni < 4; ++ni)
          acc[mi][ni] = __builtin_amdgcn_mfma_f32_16x16x32_bf16(af[mi], bfr[ni], acc[mi][ni], 0, 0, 0);
    }
    __syncthreads();
  }

  u16* Ubase = U + (m0 + wm) * (size_t)H + n0 + wn;
  #pragma unroll
  for (int mi = 0; mi < 4; ++mi)
    #pragma unroll
    for (int ni = 0; ni < 4; ++ni)
      #pragma unroll
      for (int v = 0; v < 4; ++v)
        Ubase[(size_t)(mi * 16 + fq * 4 + v) * H + ni * 16 + fr] = f2bf(acc[mi][ni][v]);
}

// ---- kernel 3: merged {wemb f32->bf16} + {zero-fill inactive out rows} ----
// blocks [0,2048): zfill row; blocks [2048, 2048+6000): conv chunk of 1024 float4.
// (round-4/5 BUG was here: 1500 blocks only covered 1/4 of wemb -> 3/4 of wemb_bf poison)
__global__ void convzfill_kernel(const float* __restrict__ wemb, u16* __restrict__ wemb_bf,
                                 const int* __restrict__ split, const int* __restrict__ nch,
                                 float* __restrict__ out) {
  int b = blockIdx.x;
  if (b < MROWS) {
    int bb = b >> 9, c = (b >> 5) & 15, t = b & 31;
    if (c < nch[bb] && t < split[bb * 16 + c]) return;   // active -> gemm writes it
    float4 z = {0.f, 0.f, 0.f, 0.f};
    float4* p = reinterpret_cast<float4*>(out + (size_t)b * V);
    for (int i = threadIdx.x; i < V / 4; i += 256) p[i] = z;
  } else {
    int base = (b - MROWS) * 1024;     // float4 index; 6000 blocks * 1024 = 6,144,000 = V*H/4
    const float4* in4 = reinterpret_cast<const float4*>(wemb);
    ushort4* out4 = reinterpret_cast<ushort4*>(wemb_bf);
    #pragma unroll
    for (int j = 0; j < 4; ++j) {
      int i = base + j * 256 + threadIdx.x;
      float4 v = in4[i];
      ushort4 o;
      o.x = f2bf(v.x); o.y = f2bf(v.y); o.z = f2bf(v.z); o.w = f2bf(v.w);
      out4[i] = o;
    }
  }
}

// ---- kernel 4: main GEMM, 256x256 tile, 8 waves, BK=32, 3-buffer counted-vmcnt pipeline ----
// LDS swizzle (both-sides, rule #21): LDS[r][slot s] holds global chunk s^((r>>1)&3);
// read-side XORs the same -> slot fq^((fr>>1)&3) yields global chunk fq for every frag row.
__device__ __forceinline__ void g8_stage(const u16* __restrict__ Abase,
                                         const u16* __restrict__ Bbase,
                                         int kt, u16* as, u16* bs, int tid) {
  const int rih = tid >> 2;                  // 0..127
  const int s = tid & 3;
  const int ssw = s ^ ((rih >> 1) & 3);      // pre-swizzled global chunk
  const int kelem = kt * 32 + ssw * 8;
  const u16* ga0 = Abase + (size_t)rih * H + kelem;
  const u16* ga1 = Abase + (size_t)(rih + 128) * H + kelem;
  const u16* gb0 = Bbase + (size_t)rih * H + kelem;
  const u16* gb1 = Bbase + (size_t)(rih + 128) * H + kelem;
  u16* la = as + rih * 32 + s * 8;           // linear dest = wave-base + lane*16B
  u16* lb = bs + rih * 32 + s * 8;
  __builtin_amdgcn_global_load_lds((gp1_t)ga0, (lp3_t)la, 16, 0, 0);
  __builtin_amdgcn_global_load_lds((gp1_t)ga1, (lp3_t)(la + 128 * 32), 16, 0, 0);
  __builtin_amdgcn_global_load_lds((gp1_t)gb0, (lp3_t)lb, 16, 0, 0);
  __builtin_amdgcn_global_load_lds((gp1_t)gb1, (lp3_t)(lb + 128 * 32), 16, 0, 0);
}

__global__ __launch_bounds__(512, 1) void gemm8_kernel(const u16* __restrict__ A,
                                                       const u16* __restrict__ Bm,
                                                       const int* __restrict__ row_list,
                                                       const int* __restrict__ count,
                                                       float* __restrict__ C) {
  const int cnt = *count;
  const int m0i = blockIdx.y * 256;
  if (m0i >= cnt) return;                    // uniform per block
  __shared__ u16 As[3][8192];                // 3 x 256x32 bf16 = 48 KiB
  __shared__ u16 Bs[3][8192];                // 48 KiB
  __shared__ int rowmap[256];
  const int tid = threadIdx.x;
  if (tid < 256) rowmap[tid] = (m0i + tid < cnt) ? row_list[m0i + tid] : -1;
  const int wave = tid >> 6;
  const int lane = tid & 63;
  const int fr = lane & 15;
  const int fq = lane >> 4;
  const int mh = wave >> 2;                  // 0..1  (M half: 128 rows)
  const int wn4 = wave & 3;                  // 0..3  (N quarter: 64 cols)
  const size_t n0 = (size_t)blockIdx.x * 256;
  const u16* Abase = A + (size_t)m0i * H;
  const u16* Bbase = Bm + n0 * H;
  const int swz = fq ^ ((fr >> 1) & 3);
  const int aoff = (mh * 128 + fr) * 32 + swz * 8;
  const int boff = (wn4 * 64 + fr) * 32 + swz * 8;

  f32x4 acc[8][4];
  const f32x4 z = {0.f, 0.f, 0.f, 0.f};
  #pragma unroll
  for (int i = 0; i < 8; ++i)
    #pragma unroll
    for (int j = 0; j < 4; ++j) acc[i][j] = z;

  u16 *a0 = As[0], *a1 = As[1], *a2 = As[2];
  u16 *b0 = Bs[0], *b1 = Bs[1], *b2 = Bs[2];
  g8_stage(Abase, Bbase, 0, a0, b0, tid);
  g8_stage(Abase, Bbase, 1, a1, b1, tid);

  for (int t = 0; t < 24; ++t) {
    // prefetch tile t+2 into the buffer freed at the end of iter t-1
    g8_stage(Abase, Bbase, (t + 2 < 24) ? t + 2 : 0, a2, b2, tid);
    // counted wait: <=12 outstanding -> 8 leaves tile t's 4 loads retired (in-order vmcnt)
    asm volatile("s_waitcnt vmcnt(8)" ::: "memory");
    __builtin_amdgcn_s_barrier();
    __builtin_amdgcn_sched_barrier(0);       // rule #18: pin ds_reads below the barrier

    bf16x8 av[4], bv[4];
    #pragma unroll
    for (int ni = 0; ni < 4; ++ni)
      bv[ni] = *reinterpret_cast<const bf16x8*>(b0 + boff + ni * 512);
    #pragma unroll
    for (int mi = 0; mi < 4; ++mi)
      av[mi] = *reinterpret_cast<const bf16x8*>(a0 + aoff + mi * 512);
    __builtin_amdgcn_s_setprio(1);
    #pragma unroll
    for (int mi = 0; mi < 4; ++mi)
      #pragma unroll
      for (int ni = 0; ni < 4; ++ni)
        acc[mi][ni] = __builtin_amdgcn_mfma_f32_16x16x32_bf16(av[mi], bv[ni], acc[mi][ni], 0, 0, 0);
    __builtin_amdgcn_s_setprio(0);
    #pragma unroll
    for (int mi = 0; mi < 4; ++mi)
      av[mi] = *reinterpret_cast<const bf16x8*>(a0 + aoff + (mi + 4) * 512);
    __builtin_amdgcn_s_setprio(1);
    #pragma unroll
    for (int mi = 0; mi < 4; ++mi)
      #pragma unroll
      for (int ni = 0; ni < 4; ++ni)
        acc[mi + 4][ni] = __builtin_amdgcn_mfma_f32_16x16x32_bf16(av[mi], bv[ni], acc[mi + 4][ni], 0, 0, 0);
    __builtin_amdgcn_s_setprio(0);

    // all this wave's ds_reads of tile t done -> after barrier, buffer reuse is safe
    asm volatile("s_waitcnt lgkmcnt(0)" ::: "memory");
    __builtin_amdgcn_s_barrier();
    __builtin_amdgcn_sched_barrier(0);
    u16* ta = a0; a0 = a1; a1 = a2; a2 = ta;
    u16* tb = b0; b0 = b1; b1 = b2; b2 = tb;
  }

  // C/D layout: col = lane&15, row = (lane>>4)*4 + v; scatter rows via rowmap
  #pragma unroll
  for (int mi = 0; mi < 8; ++mi) {
    #pragma unroll
    for (int v = 0; v < 4; ++v) {
      int m = mh * 128 + mi * 16 + fq * 4 + v;
      int orow = rowmap[m];
      if (orow < 0) continue;
      float* cb = C + (size_t)orow * V + n0 + wn4 * 64;
      #pragma unroll
      for (int ni = 0; ni < 4; ++ni)
        cb[ni * 16 + fr] = acc[mi][ni][v];
    }
  }
}

extern "C" void kernel_launch(void* const* d_in, const int* in_sizes, int n_in,
                              void* d_out, int out_size, void* d_ws, size_t ws_size,
                              hipStream_t stream) {
  const int* tok    = (const int*)d_in[0];    // (4,16,33) int32
  const int* split  = (const int*)d_in[1];    // (4,16) int32
  const int* nch    = (const int*)d_in[2];    // (4,) int32
  // d_in[3] chunk_units, d_in[5] chunk_sos_embedding: provably dead w.r.t. output
  const float* wemb = (const float*)d_in[4];  // (32000,768) f32
  const float* wdec = (const float*)d_in[6];  // (768,768) f32
  float* out = (float*)d_out;                 // (4,16,32,32000) f32

  char* ws = (char*)d_ws;
  u16* wemb_bf  = (u16*)ws;                                   // 49,152,000 B
  u16* u        = (u16*)(ws + 49152000);                      //  3,145,728 B
  u16* e_bf     = (u16*)(ws + 49152000 + 3145728);            //  3,145,728 B
  u16* wdecT    = (u16*)(ws + 49152000 + 2 * 3145728);        //  1,179,648 B
  int* row_list = (int*)(ws + 49152000 + 2 * 3145728 + 1179648);
  int* count    = row_list + MROWS;

  prep_kernel<<<1, 256, 0, stream>>>(split, nch, row_list, count);
  prep2_kernel<<<144 + MROWS, 256, 0, stream>>>(wdec, wdecT, tok, wemb, row_list, count, e_bf);
  udec_gemm_kernel<<<dim3(H / UBN, MROWS / UBM), 256, 0, stream>>>(e_bf, wdecT, count, u);
  convzfill_kernel<<<MROWS + 6000, 256, 0, stream>>>(wemb, wemb_bf, split, nch, out);
  gemm8_kernel<<<dim3(V / 256, MROWS / 256), 512, 0, stream>>>(u, wemb_bf, row_list, count, out);
}

// Round 7
// 120.919 us; speedup vs baseline: 2.9181x; 1.1596x over previous
//
#include <hip/hip_runtime.h>

typedef unsigned short u16;
typedef unsigned int u32;
typedef __attribute__((ext_vector_type(4))) float f32x4;
typedef __attribute__((ext_vector_type(8))) short bf16x8;
typedef __attribute__((address_space(1))) const u32* gp1_t;
typedef __attribute__((address_space(3))) u32* lp3_t;

#define H 768
#define V 32000
#define MROWS 2048   // B*C*32 = 4*16*32
#define NGEMM 1000   // 125 N-tiles x 8 M-tiles
#define NT 24        // 768 / 32

__device__ __forceinline__ u16 f2bf(float f) {
  u32 x = __float_as_uint(f);
  x += 0x7fffu + ((x >> 16) & 1u);   // round-to-nearest-even
  return (u16)(x >> 16);
}

__device__ __forceinline__ bf16x8 pack8(float4 a, float4 b) {
  bf16x8 r;
  r[0] = (short)f2bf(a.x); r[1] = (short)f2bf(a.y);
  r[2] = (short)f2bf(a.z); r[3] = (short)f2bf(a.w);
  r[4] = (short)f2bf(b.x); r[5] = (short)f2bf(b.y);
  r[6] = (short)f2bf(b.z); r[7] = (short)f2bf(b.w);
  return r;
}

// ---- kernel 0: compact list of active rows ----
__global__ void prep_kernel(const int* __restrict__ split, const int* __restrict__ nch,
                            int* __restrict__ row_list, int* __restrict__ count) {
  __shared__ int cnt;
  if (threadIdx.x == 0) cnt = 0;
  __syncthreads();
  for (int row = threadIdx.x; row < MROWS; row += blockDim.x) {
    int b = row >> 9;
    int c = (row >> 5) & 15;
    int t = row & 31;
    if (c < nch[b] && t < split[b * 16 + c]) {
      int slot = atomicAdd(&cnt, 1);
      row_list[slot] = row;
    }
  }
  __syncthreads();
  if (threadIdx.x == 0) *count = cnt;
}

// ---- kernel 1: merged {W_dec transpose->bf16} + {E-row gather->bf16} ----
__global__ void prep2_kernel(const float* __restrict__ wdec, u16* __restrict__ wdecT,
                             const int* __restrict__ tok_ids, const float* __restrict__ wemb,
                             const int* __restrict__ row_list, const int* __restrict__ count,
                             u16* __restrict__ e_bf) {
  if (blockIdx.x < 144) {
    __shared__ float tile[64][65];
    int b = blockIdx.x;
    int hb = (b / 12) * 64, jb = (b % 12) * 64;
    #pragma unroll
    for (int rr = 0; rr < 64; rr += 16) {
      int r = rr + (threadIdx.x >> 4);
      int c = (threadIdx.x & 15) * 4;
      float4 v = *reinterpret_cast<const float4*>(&wdec[(size_t)(hb + r) * H + jb + c]);
      tile[r][c] = v.x; tile[r][c + 1] = v.y; tile[r][c + 2] = v.z; tile[r][c + 3] = v.w;
    }
    __syncthreads();
    #pragma unroll
    for (int rr = 0; rr < 64; rr += 16) {
      int r = rr + (threadIdx.x >> 4);      // j
      int c = (threadIdx.x & 15) * 4;       // h group
      ushort4 o;
      o.x = f2bf(tile[c][r]); o.y = f2bf(tile[c + 1][r]);
      o.z = f2bf(tile[c + 2][r]); o.w = f2bf(tile[c + 3][r]);
      *reinterpret_cast<ushort4*>(&wdecT[(size_t)(jb + r) * H + hb + c]) = o;
    }
  } else {
    int s = blockIdx.x - 144;
    int cnt = *count;
    int c4 = threadIdx.x * 4;
    if (c4 >= H) return;
    ushort4 o = {0, 0, 0, 0};
    if (s < cnt) {
      int row = row_list[s];
      int tok = tok_ids[(row >> 5) * 33 + (row & 31)];
      float4 v = *reinterpret_cast<const float4*>(&wemb[(size_t)tok * H + c4]);
      o.x = f2bf(v.x); o.y = f2bf(v.y); o.z = f2bf(v.z); o.w = f2bf(v.w);
    }
    *reinterpret_cast<ushort4*>(&e_bf[(size_t)s * H + c4]) = o;
  }
}

// ---- kernel 2: u[slot,:] = E[slot,:] x WdecT^T (bf16 MFMA) — proven 128^2 structure ----
#define UBM 128
#define UBN 128
#define UBK 64

__global__ __launch_bounds__(256) void udec_gemm_kernel(const u16* __restrict__ A,
                                                        const u16* __restrict__ Bm,
                                                        const int* __restrict__ count,
                                                        u16* __restrict__ U) {
  const int cnt = *count;
  const int m0i = blockIdx.y * UBM;
  if (m0i >= cnt) return;
  __shared__ u16 As[UBM * UBK];
  __shared__ u16 Bs[UBN * UBK];
  const int tid = threadIdx.x;
  const int wave = tid >> 6;
  const int lane = tid & 63;
  const int wm = (wave >> 1) * 64;
  const int wn = (wave & 1) * 64;
  const int fr = lane & 15;
  const int fq = lane >> 4;
  const size_t m0 = (size_t)m0i;
  const size_t n0 = (size_t)blockIdx.x * UBN;
  const u16* Abase = A + m0 * H;
  const u16* Bbase = Bm + n0 * H;

  f32x4 acc[4][4];
  const f32x4 z = {0.f, 0.f, 0.f, 0.f};
  #pragma unroll
  for (int i = 0; i < 4; ++i)
    #pragma unroll
    for (int j = 0; j < 4; ++j) acc[i][j] = z;

  for (int k0 = 0; k0 < H; k0 += UBK) {
    #pragma unroll
    for (int i = 0; i < 4; ++i) {
      int e = (i * 256 + tid) * 8;
      int row = e >> 6;
      int col = e & 63;
      __builtin_amdgcn_global_load_lds((gp1_t)(Abase + (size_t)row * H + k0 + col),
                                       (lp3_t)(&As[e]), 16, 0, 0);
      __builtin_amdgcn_global_load_lds((gp1_t)(Bbase + (size_t)row * H + k0 + col),
                                       (lp3_t)(&Bs[e]), 16, 0, 0);
    }
    __syncthreads();
    #pragma unroll
    for (int kk = 0; kk < UBK; kk += 32) {
      bf16x8 af[4], bfr[4];
      #pragma unroll
      for (int mi = 0; mi < 4; ++mi)
        af[mi] = *reinterpret_cast<const bf16x8*>(&As[(wm + mi * 16 + fr) * UBK + kk + fq * 8]);
      #pragma unroll
      for (int ni = 0; ni < 4; ++ni)
        bfr[ni] = *reinterpret_cast<const bf16x8*>(&Bs[(wn + ni * 16 + fr) * UBK + kk + fq * 8]);
      #pragma unroll
      for (int mi = 0; mi < 4; ++mi)
        #pragma unroll
        for (int ni = 0; ni < 4; ++ni)
          acc[mi][ni] = __builtin_amdgcn_mfma_f32_16x16x32_bf16(af[mi], bfr[ni], acc[mi][ni], 0, 0, 0);
    }
    __syncthreads();
  }

  u16* Ubase = U + (m0 + wm) * (size_t)H + n0 + wn;
  #pragma unroll
  for (int mi = 0; mi < 4; ++mi)
    #pragma unroll
    for (int ni = 0; ni < 4; ++ni)
      #pragma unroll
      for (int v = 0; v < 4; ++v)
        Ubase[(size_t)(mi * 16 + fq * 4 + v) * H + ni * 16 + fr] = f2bf(acc[mi][ni][v]);
}

// ---- kernel 3: FUSED {main GEMM (f32-B, in-kernel bf16 cvt)} + {zero-fill inactive rows} ----
// Blocks [0,1000): 256x256 GEMM tile, 8 waves, BK=32, 2-buffer 2-phase (T3-minimum template).
// Blocks [1000,1000+2048): zero one output row if inactive. 64KB LDS -> 2 blocks/CU,
// so zfill blocks co-reside with GEMM blocks and their writes hide under compute.
// LDS swizzle (both-sides, rule #21): slot s at row r holds global chunk s^((r>>1)&3);
// A: pre-swizzled global source for global_load_lds; B: swizzled ds_write addr (reg-staged).
__global__ __launch_bounds__(512, 1) void fused_kernel(const u16* __restrict__ A,
                                                       const float* __restrict__ Wf,
                                                       const int* __restrict__ row_list,
                                                       const int* __restrict__ count,
                                                       const int* __restrict__ split,
                                                       const int* __restrict__ nch,
                                                       float* __restrict__ C) {
  const int flat = blockIdx.x;
  if (flat >= NGEMM) {
    int row = flat - NGEMM;
    int b = row >> 9, c = (row >> 5) & 15, t = row & 31;
    if (c < nch[b] && t < split[b * 16 + c]) return;   // active -> gemm writes it
    float4 z = {0.f, 0.f, 0.f, 0.f};
    float4* p = reinterpret_cast<float4*>(C + (size_t)row * V);
    for (int i = threadIdx.x; i < V / 4; i += 512) p[i] = z;
    return;
  }
  const int cnt = *count;
  const int my = flat / 125;
  const int nx = flat % 125;
  const int m0i = my * 256;
  if (m0i >= cnt) return;                    // uniform per block

  __shared__ __align__(16) u16 As[2][8192];  // 2 x 256x32 bf16 = 32 KiB
  __shared__ __align__(16) u16 Bs[2][8192];  // 32 KiB
  __shared__ int rowmap[256];
  const int tid = threadIdx.x;
  if (tid < 256) rowmap[tid] = (m0i + tid < cnt) ? row_list[m0i + tid] : -1;
  const int wave = tid >> 6;
  const int lane = tid & 63;
  const int fr = lane & 15;
  const int fq = lane >> 4;
  const int mh = wave >> 2;                  // 0..1  (M half: 128 rows)
  const int wn4 = wave & 3;                  // 0..3  (N quarter: 64 cols)
  const size_t n0 = (size_t)nx * 256;
  const u16* Abase = A + (size_t)m0i * H;
  const float* Bfbase = Wf + n0 * H;
  // staging thread mapping
  const int rih = tid >> 2;                  // 0..127
  const int s = tid & 3;
  const int ssw = s ^ ((rih >> 1) & 3);      // pre-swizzled chunk
  // read-side swizzle
  const int swz = fq ^ ((fr >> 1) & 3);
  const int aoff = (mh * 128 + fr) * 32 + swz * 8;
  const int boff = (wn4 * 64 + fr) * 32 + swz * 8;

  f32x4 acc[8][4];
  const f32x4 z = {0.f, 0.f, 0.f, 0.f};
  #pragma unroll
  for (int i = 0; i < 8; ++i)
    #pragma unroll
    for (int j = 0; j < 4; ++j) acc[i][j] = z;

  // prologue: stage tile 0 into buffer 0
  {
    const int kelem = ssw * 8;
    __builtin_amdgcn_global_load_lds((gp1_t)(Abase + (size_t)rih * H + kelem),
                                     (lp3_t)(&As[0][rih * 32 + s * 8]), 16, 0, 0);
    __builtin_amdgcn_global_load_lds((gp1_t)(Abase + (size_t)(rih + 128) * H + kelem),
                                     (lp3_t)(&As[0][(rih + 128) * 32 + s * 8]), 16, 0, 0);
    float4 b0 = *reinterpret_cast<const float4*>(Bfbase + (size_t)rih * H + kelem);
    float4 b1 = *reinterpret_cast<const float4*>(Bfbase + (size_t)rih * H + kelem + 4);
    float4 b2 = *reinterpret_cast<const float4*>(Bfbase + (size_t)(rih + 128) * H + kelem);
    float4 b3 = *reinterpret_cast<const float4*>(Bfbase + (size_t)(rih + 128) * H + kelem + 4);
    *reinterpret_cast<bf16x8*>(&Bs[0][rih * 32 + s * 8]) = pack8(b0, b1);
    *reinterpret_cast<bf16x8*>(&Bs[0][(rih + 128) * 32 + s * 8]) = pack8(b2, b3);
  }
  __syncthreads();

  for (int t = 0; t < NT; ++t) {
    u16* curA = As[t & 1];
    u16* curB = Bs[t & 1];
    u16* nxtA = As[(t + 1) & 1];
    u16* nxtB = Bs[(t + 1) & 1];
    const bool more = (t + 1 < NT);
    float4 b0, b1, b2, b3;
    if (more) {
      const int kelem = (t + 1) * 32 + ssw * 8;
      __builtin_amdgcn_global_load_lds((gp1_t)(Abase + (size_t)rih * H + kelem),
                                       (lp3_t)(nxtA + rih * 32 + s * 8), 16, 0, 0);
      __builtin_amdgcn_global_load_lds((gp1_t)(Abase + (size_t)(rih + 128) * H + kelem),
                                       (lp3_t)(nxtA + (rih + 128) * 32 + s * 8), 16, 0, 0);
      b0 = *reinterpret_cast<const float4*>(Bfbase + (size_t)rih * H + kelem);
      b1 = *reinterpret_cast<const float4*>(Bfbase + (size_t)rih * H + kelem + 4);
      b2 = *reinterpret_cast<const float4*>(Bfbase + (size_t)(rih + 128) * H + kelem);
      b3 = *reinterpret_cast<const float4*>(Bfbase + (size_t)(rih + 128) * H + kelem + 4);
    }

    bf16x8 av[4], bv[4];
    #pragma unroll
    for (int ni = 0; ni < 4; ++ni)
      bv[ni] = *reinterpret_cast<const bf16x8*>(curB + boff + ni * 512);
    #pragma unroll
    for (int mi = 0; mi < 4; ++mi)
      av[mi] = *reinterpret_cast<const bf16x8*>(curA + aoff + mi * 512);
    __builtin_amdgcn_s_setprio(1);
    #pragma unroll
    for (int mi = 0; mi < 4; ++mi)
      #pragma unroll
      for (int ni = 0; ni < 4; ++ni)
        acc[mi][ni] = __builtin_amdgcn_mfma_f32_16x16x32_bf16(av[mi], bv[ni], acc[mi][ni], 0, 0, 0);
    __builtin_amdgcn_s_setprio(0);
    #pragma unroll
    for (int mi = 0; mi < 4; ++mi)
      av[mi] = *reinterpret_cast<const bf16x8*>(curA + aoff + (mi + 4) * 512);
    __builtin_amdgcn_s_setprio(1);
    #pragma unroll
    for (int mi = 0; mi < 4; ++mi)
      #pragma unroll
      for (int ni = 0; ni < 4; ++ni)
        acc[mi + 4][ni] = __builtin_amdgcn_mfma_f32_16x16x32_bf16(av[mi], bv[ni], acc[mi + 4][ni], 0, 0, 0);
    __builtin_amdgcn_s_setprio(0);

    if (more) {
      *reinterpret_cast<bf16x8*>(nxtB + rih * 32 + s * 8) = pack8(b0, b1);
      *reinterpret_cast<bf16x8*>(nxtB + (rih + 128) * 32 + s * 8) = pack8(b2, b3);
    }
    __syncthreads();   // drains gload_lds(A,t+1) + ds_writes(B,t+1) + all reads of cur
  }

  // C/D layout: col = lane&15, row = (lane>>4)*4 + v; scatter rows via rowmap
  #pragma unroll
  for (int mi = 0; mi < 8; ++mi) {
    #pragma unroll
    for (int v = 0; v < 4; ++v) {
      int m = mh * 128 + mi * 16 + fq * 4 + v;
      int orow = rowmap[m];
      if (orow < 0) continue;
      float* cb = C + (size_t)orow * V + n0 + wn4 * 64;
      #pragma unroll
      for (int ni = 0; ni < 4; ++ni)
        cb[ni * 16 + fr] = acc[mi][ni][v];
    }
  }
}

extern "C" void kernel_launch(void* const* d_in, const int* in_sizes, int n_in,
                              void* d_out, int out_size, void* d_ws, size_t ws_size,
                              hipStream_t stream) {
  const int* tok    = (const int*)d_in[0];    // (4,16,33) int32
  const int* split  = (const int*)d_in[1];    // (4,16) int32
  const int* nch    = (const int*)d_in[2];    // (4,) int32
  // d_in[3] chunk_units, d_in[5] chunk_sos_embedding: provably dead w.r.t. output
  const float* wemb = (const float*)d_in[4];  // (32000,768) f32
  const float* wdec = (const float*)d_in[6];  // (768,768) f32
  float* out = (float*)d_out;                 // (4,16,32,32000) f32

  char* ws = (char*)d_ws;
  u16* u        = (u16*)ws;                                   // 3,145,728 B
  u16* e_bf     = (u16*)(ws + 3145728);                       // 3,145,728 B
  u16* wdecT    = (u16*)(ws + 2 * 3145728);                   // 1,179,648 B
  int* row_list = (int*)(ws + 2 * 3145728 + 1179648);
  int* count    = row_list + MROWS;

  prep_kernel<<<1, 256, 0, stream>>>(split, nch, row_list, count);
  prep2_kernel<<<144 + MROWS, 256, 0, stream>>>(wdec, wdecT, tok, wemb, row_list, count, e_bf);
  udec_gemm_kernel<<<dim3(H / UBN, MROWS / UBM), 256, 0, stream>>>(e_bf, wdecT, count, u);
  fused_kernel<<<NGEMM + MROWS, 512, 0, stream>>>(u, wemb, row_list, count, split, nch, out);
}

// Round 9
// 115.899 us; speedup vs baseline: 3.0445x; 1.0433x over previous
//
#include <hip/hip_runtime.h>

typedef unsigned short u16;
typedef unsigned int u32;
typedef __attribute__((ext_vector_type(4))) float f32x4;
typedef __attribute__((ext_vector_type(8))) short bf16x8;
typedef __attribute__((address_space(1))) const u32* gp1_t;
typedef __attribute__((address_space(3))) u32* lp3_t;

#define H 768
#define V 32000
#define MROWS 2048   // B*C*32 = 4*16*32
#define NGEMM 1000   // 8 M-tiles x 125 N-tiles
#define NT 24        // 768 / 32

__device__ __forceinline__ u16 f2bf(float f) {
  u32 x = __float_as_uint(f);
  x += 0x7fffu + ((x >> 16) & 1u);   // round-to-nearest-even
  return (u16)(x >> 16);
}

__device__ __forceinline__ bf16x8 pack8(float4 a, float4 b) {
  bf16x8 r;
  r[0] = (short)f2bf(a.x); r[1] = (short)f2bf(a.y);
  r[2] = (short)f2bf(a.z); r[3] = (short)f2bf(a.w);
  r[4] = (short)f2bf(b.x); r[5] = (short)f2bf(b.y);
  r[6] = (short)f2bf(b.z); r[7] = (short)f2bf(b.w);
  return r;
}

// Deterministic compaction: active rows sorted by (b,c,t). pre[j] = exclusive prefix
// over the 64 chunks' active counts; pre[64] = cnt. ~200 cycles per block.
__device__ __forceinline__ int build_prefix(const int* __restrict__ split,
                                            const int* __restrict__ nch,
                                            int* pre, int tid) {
  if (tid < 64) {
    int b = tid >> 4, c = tid & 15;
    int sz = (c < nch[b]) ? split[tid] : 0;
    pre[tid] = sz < 32 ? sz : 32;
  }
  __syncthreads();
  if (tid == 0) {
    int acc = 0;
    #pragma unroll
    for (int i = 0; i < 64; ++i) { int v = pre[i]; pre[i] = acc; acc += v; }
    pre[64] = acc;
  }
  __syncthreads();
  return pre[64];
}

__device__ __forceinline__ int slot2row(const int* pre, int s) {
  int lo = 0, hi = 63;
  while (lo < hi) { int mid = (lo + hi + 1) >> 1; if (pre[mid] <= s) lo = mid; else hi = mid - 1; }
  return lo * 32 + (s - pre[lo]);   // (b*16+c)*32 + t
}

// ---- kernel A: merged {W_dec transpose->bf16} + {E-row gather->bf16, local compaction} ----
__global__ void prepA_kernel(const float* __restrict__ wdec, u16* __restrict__ wdecT,
                             const int* __restrict__ tok_ids, const float* __restrict__ wemb,
                             const int* __restrict__ split, const int* __restrict__ nch,
                             u16* __restrict__ e_bf) {
  if (blockIdx.x < 144) {
    __shared__ float tile[64][65];
    int b = blockIdx.x;
    int hb = (b / 12) * 64, jb = (b % 12) * 64;
    #pragma unroll
    for (int rr = 0; rr < 64; rr += 16) {
      int r = rr + (threadIdx.x >> 4);
      int c = (threadIdx.x & 15) * 4;
      float4 v = *reinterpret_cast<const float4*>(&wdec[(size_t)(hb + r) * H + jb + c]);
      tile[r][c] = v.x; tile[r][c + 1] = v.y; tile[r][c + 2] = v.z; tile[r][c + 3] = v.w;
    }
    __syncthreads();
    #pragma unroll
    for (int rr = 0; rr < 64; rr += 16) {
      int r = rr + (threadIdx.x >> 4);      // j
      int c = (threadIdx.x & 15) * 4;       // h group
      ushort4 o;
      o.x = f2bf(tile[c][r]); o.y = f2bf(tile[c + 1][r]);
      o.z = f2bf(tile[c + 2][r]); o.w = f2bf(tile[c + 3][r]);
      *reinterpret_cast<ushort4*>(&wdecT[(size_t)(jb + r) * H + hb + c]) = o;
    }
  } else {
    __shared__ int pre[65];
    int tid = threadIdx.x;
    int cnt = build_prefix(split, nch, pre, tid);
    int s = blockIdx.x - 144;
    int c4 = tid * 4;
    if (c4 >= H) return;
    ushort4 o = {0, 0, 0, 0};
    if (s < cnt) {
      int row = slot2row(pre, s);
      int tok = tok_ids[(row >> 5) * 33 + (row & 31)];
      float4 v = *reinterpret_cast<const float4*>(&wemb[(size_t)tok * H + c4]);
      o.x = f2bf(v.x); o.y = f2bf(v.y); o.z = f2bf(v.z); o.w = f2bf(v.w);
    }
    *reinterpret_cast<ushort4*>(&e_bf[(size_t)s * H + c4]) = o;
  }
}

// ---- kernel B: u[slot,:] = E[slot,:] x WdecT^T (bf16 MFMA) — proven 128^2 structure ----
#define UBM 128
#define UBN 128
#define UBK 64

__global__ __launch_bounds__(256) void udec_gemm_kernel(const u16* __restrict__ A,
                                                        const u16* __restrict__ Bm,
                                                        const int* __restrict__ split,
                                                        const int* __restrict__ nch,
                                                        u16* __restrict__ U) {
  __shared__ int pre[65];
  const int tid = threadIdx.x;
  const int cnt = build_prefix(split, nch, pre, tid);
  const int m0i = blockIdx.y * UBM;
  if (m0i >= cnt) return;
  __shared__ u16 As[UBM * UBK];
  __shared__ u16 Bs[UBN * UBK];
  const int wave = tid >> 6;
  const int lane = tid & 63;
  const int wm = (wave >> 1) * 64;
  const int wn = (wave & 1) * 64;
  const int fr = lane & 15;
  const int fq = lane >> 4;
  const size_t m0 = (size_t)m0i;
  const size_t n0 = (size_t)blockIdx.x * UBN;
  const u16* Abase = A + m0 * H;
  const u16* Bbase = Bm + n0 * H;

  f32x4 acc[4][4];
  const f32x4 z = {0.f, 0.f, 0.f, 0.f};
  #pragma unroll
  for (int i = 0; i < 4; ++i)
    #pragma unroll
    for (int j = 0; j < 4; ++j) acc[i][j] = z;

  for (int k0 = 0; k0 < H; k0 += UBK) {
    #pragma unroll
    for (int i = 0; i < 4; ++i) {
      int e = (i * 256 + tid) * 8;
      int row = e >> 6;
      int col = e & 63;
      __builtin_amdgcn_global_load_lds((gp1_t)(Abase + (size_t)row * H + k0 + col),
                                       (lp3_t)(&As[e]), 16, 0, 0);
      __builtin_amdgcn_global_load_lds((gp1_t)(Bbase + (size_t)row * H + k0 + col),
                                       (lp3_t)(&Bs[e]), 16, 0, 0);
    }
    __syncthreads();
    #pragma unroll
    for (int kk = 0; kk < UBK; kk += 32) {
      bf16x8 af[4], bfr[4];
      #pragma unroll
      for (int mi = 0; mi < 4; ++mi)
        af[mi] = *reinterpret_cast<const bf16x8*>(&As[(wm + mi * 16 + fr) * UBK + kk + fq * 8]);
      #pragma unroll
      for (int ni = 0; ni < 4; ++ni)
        bfr[ni] = *reinterpret_cast<const bf16x8*>(&Bs[(wn + ni * 16 + fr) * UBK + kk + fq * 8]);
      #pragma unroll
      for (int mi = 0; mi < 4; ++mi)
        #pragma unroll
        for (int ni = 0; ni < 4; ++ni)
          acc[mi][ni] = __builtin_amdgcn_mfma_f32_16x16x32_bf16(af[mi], bfr[ni], acc[mi][ni], 0, 0, 0);
    }
    __syncthreads();
  }

  u16* Ubase = U + (m0 + wm) * (size_t)H + n0 + wn;
  #pragma unroll
  for (int mi = 0; mi < 4; ++mi)
    #pragma unroll
    for (int ni = 0; ni < 4; ++ni)
      #pragma unroll
      for (int v = 0; v < 4; ++v)
        Ubase[(size_t)(mi * 16 + fq * 4 + v) * H + ni * 16 + fr] = f2bf(acc[mi][ni][v]);
}

// ---- kernel C: FUSED {main GEMM (f32-B, in-kernel bf16 cvt)} + {zero-fill inactive rows} ----
// Blocks [0,1000): 256x256 GEMM tile, 8 waves, BK=32, 2-buffer 2-phase, local compaction.
// Blocks [1000,1000+2048): zero one output row if inactive. ~67KB LDS -> 2 blocks/CU.
// All output stores nontemporal: keeps wemb L3-resident for the 2nd M-tile's B reads.
__global__ __launch_bounds__(512, 1) void fused_kernel(const u16* __restrict__ A,
                                                       const float* __restrict__ Wf,
                                                       const int* __restrict__ split,
                                                       const int* __restrict__ nch,
                                                       float* __restrict__ C) {
  const int flat = blockIdx.x;
  if (flat >= NGEMM) {
    int row = flat - NGEMM;
    int b = row >> 9, c = (row >> 5) & 15, t = row & 31;
    if (c < nch[b] && t < split[b * 16 + c]) return;   // active -> gemm writes it
    const f32x4 z = {0.f, 0.f, 0.f, 0.f};
    f32x4* p = reinterpret_cast<f32x4*>(C + (size_t)row * V);
    for (int i = threadIdx.x; i < V / 4; i += 512)
      __builtin_nontemporal_store(z, p + i);
    return;
  }
  __shared__ int pre[65];
  __shared__ int rowmap[256];
  const int tid = threadIdx.x;
  const int cnt = build_prefix(split, nch, pre, tid);
  const int my = flat / 125;
  const int nx = flat % 125;
  const int m0i = my * 256;
  if (m0i >= cnt) return;                    // uniform per block
  if (tid < 256) {
    int s = m0i + tid;
    rowmap[tid] = (s < cnt) ? slot2row(pre, s) : -1;
  }
  // rowmap consumed only in the epilogue; K-loop barriers order it.

  __shared__ __align__(16) u16 As[2][8192];  // 2 x 256x32 bf16 = 32 KiB
  __shared__ __align__(16) u16 Bs[2][8192];  // 32 KiB
  const int wave = tid >> 6;
  const int lane = tid & 63;
  const int fr = lane & 15;
  const int fq = lane >> 4;
  const int mh = wave >> 2;                  // 0..1  (M half: 128 rows)
  const int wn4 = wave & 3;                  // 0..3  (N quarter: 64 cols)
  const size_t n0 = (size_t)nx * 256;
  const u16* Abase = A + (size_t)m0i * H;
  const float* Bfbase = Wf + n0 * H;
  // staging thread mapping
  const int rih = tid >> 2;                  // 0..127
  const int s = tid & 3;
  const int ssw = s ^ ((rih >> 1) & 3);      // pre-swizzled chunk (both-sides swizzle)
  // read-side swizzle
  const int swz = fq ^ ((fr >> 1) & 3);
  const int aoff = (mh * 128 + fr) * 32 + swz * 8;
  const int boff = (wn4 * 64 + fr) * 32 + swz * 8;

  f32x4 acc[8][4];
  const f32x4 z = {0.f, 0.f, 0.f, 0.f};
  #pragma unroll
  for (int i = 0; i < 8; ++i)
    #pragma unroll
    for (int j = 0; j < 4; ++j) acc[i][j] = z;

  // prologue: stage tile 0 into buffer 0
  {
    const int kelem = ssw * 8;
    __builtin_amdgcn_global_load_lds((gp1_t)(Abase + (size_t)rih * H + kelem),
                                     (lp3_t)(&As[0][rih * 32 + s * 8]), 16, 0, 0);
    __builtin_amdgcn_global_load_lds((gp1_t)(Abase + (size_t)(rih + 128) * H + kelem),
                                     (lp3_t)(&As[0][(rih + 128) * 32 + s * 8]), 16, 0, 0);
    float4 b0 = *reinterpret_cast<const float4*>(Bfbase + (size_t)rih * H + kelem);
    float4 b1 = *reinterpret_cast<const float4*>(Bfbase + (size_t)rih * H + kelem + 4);
    float4 b2 = *reinterpret_cast<const float4*>(Bfbase + (size_t)(rih + 128) * H + kelem);
    float4 b3 = *reinterpret_cast<const float4*>(Bfbase + (size_t)(rih + 128) * H + kelem + 4);
    *reinterpret_cast<bf16x8*>(&Bs[0][rih * 32 + s * 8]) = pack8(b0, b1);
    *reinterpret_cast<bf16x8*>(&Bs[0][(rih + 128) * 32 + s * 8]) = pack8(b2, b3);
  }
  __syncthreads();

  for (int t = 0; t < NT; ++t) {
    u16* curA = As[t & 1];
    u16* curB = Bs[t & 1];
    u16* nxtA = As[(t + 1) & 1];
    u16* nxtB = Bs[(t + 1) & 1];
    const bool more = (t + 1 < NT);
    float4 b0, b1, b2, b3;
    if (more) {
      const int kelem = (t + 1) * 32 + ssw * 8;
      __builtin_amdgcn_global_load_lds((gp1_t)(Abase + (size_t)rih * H + kelem),
                                       (lp3_t)(nxtA + rih * 32 + s * 8), 16, 0, 0);
      __builtin_amdgcn_global_load_lds((gp1_t)(Abase + (size_t)(rih + 128) * H + kelem),
                                       (lp3_t)(nxtA + (rih + 128) * 32 + s * 8), 16, 0, 0);
      b0 = *reinterpret_cast<const float4*>(Bfbase + (size_t)rih * H + kelem);
      b1 = *reinterpret_cast<const float4*>(Bfbase + (size_t)rih * H + kelem + 4);
      b2 = *reinterpret_cast<const float4*>(Bfbase + (size_t)(rih + 128) * H + kelem);
      b3 = *reinterpret_cast<const float4*>(Bfbase + (size_t)(rih + 128) * H + kelem + 4);
    }

    bf16x8 av[4], bv[4];
    #pragma unroll
    for (int ni = 0; ni < 4; ++ni)
      bv[ni] = *reinterpret_cast<const bf16x8*>(curB + boff + ni * 512);
    #pragma unroll
    for (int mi = 0; mi < 4; ++mi)
      av[mi] = *reinterpret_cast<const bf16x8*>(curA + aoff + mi * 512);
    __builtin_amdgcn_s_setprio(1);
    #pragma unroll
    for (int mi = 0; mi < 4; ++mi)
      #pragma unroll
      for (int ni = 0; ni < 4; ++ni)
        acc[mi][ni] = __builtin_amdgcn_mfma_f32_16x16x32_bf16(av[mi], bv[ni], acc[mi][ni], 0, 0, 0);
    __builtin_amdgcn_s_setprio(0);
    #pragma unroll
    for (int mi = 0; mi < 4; ++mi)
      av[mi] = *reinterpret_cast<const bf16x8*>(curA + aoff + (mi + 4) * 512);
    __builtin_amdgcn_s_setprio(1);
    #pragma unroll
    for (int mi = 0; mi < 4; ++mi)
      #pragma unroll
      for (int ni = 0; ni < 4; ++ni)
        acc[mi + 4][ni] = __builtin_amdgcn_mfma_f32_16x16x32_bf16(av[mi], bv[ni], acc[mi + 4][ni], 0, 0, 0);
    __builtin_amdgcn_s_setprio(0);

    if (more) {
      *reinterpret_cast<bf16x8*>(nxtB + rih * 32 + s * 8) = pack8(b0, b1);
      *reinterpret_cast<bf16x8*>(nxtB + (rih + 128) * 32 + s * 8) = pack8(b2, b3);
    }
    __syncthreads();   // drains gload_lds(A,t+1) + ds_writes(B,t+1) + all reads of cur
  }

  // C/D layout: col = lane&15, row = (lane>>4)*4 + v; scatter rows via rowmap (nontemporal)
  #pragma unroll
  for (int mi = 0; mi < 8; ++mi) {
    #pragma unroll
    for (int v = 0; v < 4; ++v) {
      int m = mh * 128 + mi * 16 + fq * 4 + v;
      int orow = rowmap[m];
      if (orow < 0) continue;
      float* cb = C + (size_t)orow * V + n0 + wn4 * 64;
      #pragma unroll
      for (int ni = 0; ni < 4; ++ni)
        __builtin_nontemporal_store(acc[mi][ni][v], &cb[ni * 16 + fr]);
    }
  }
}

extern "C" void kernel_launch(void* const* d_in, const int* in_sizes, int n_in,
                              void* d_out, int out_size, void* d_ws, size_t ws_size,
                              hipStream_t stream) {
  const int* tok    = (const int*)d_in[0];    // (4,16,33) int32
  const int* split  = (const int*)d_in[1];    // (4,16) int32
  const int* nch    = (const int*)d_in[2];    // (4,) int32
  // d_in[3] chunk_units, d_in[5] chunk_sos_embedding: provably dead w.r.t. output
  const float* wemb = (const float*)d_in[4];  // (32000,768) f32
  const float* wdec = (const float*)d_in[6];  // (768,768) f32
  float* out = (float*)d_out;                 // (4,16,32,32000) f32

  char* ws = (char*)d_ws;
  u16* u     = (u16*)ws;                      // 3,145,728 B
  u16* e_bf  = (u16*)(ws + 3145728);          // 3,145,728 B
  u16* wdecT = (u16*)(ws + 2 * 3145728);      // 1,179,648 B

  prepA_kernel<<<144 + MROWS, 256, 0, stream>>>(wdec, wdecT, tok, wemb, split, nch, e_bf);
  udec_gemm_kernel<<<dim3(H / UBN, MROWS / UBM), 256, 0, stream>>>(e_bf, wdecT, split, nch, u);
  fused_kernel<<<NGEMM + MROWS, 512, 0, stream>>>(u, wemb, split, nch, out);
}